// Round 10
// baseline (362.215 us; speedup 1.0000x reference)
//
#include <hip/hip_runtime.h>

#define NUM_CN   25000
#define NUM_VN   50000
#define NUM_E    200000
#define D_EMBED  16
#define D_HIDDEN 32
#define D_MSG    16
#define BATCH    16

typedef float f32x2 __attribute__((ext_vector_type(2)));

// ---------------------------------------------------------------------------
// Workspace layout (int units) — 54.41 MB total (proven available):
#define WS_IDS_X   0           // 200000  (stores FROM node ids, CSR order)
#define WS_IDS_Z   200000      // 200000
#define WS_OFF_X   400000      // 50001
#define WS_OFF_Z   450001      // 50001
#define WS_CNT_X   500002      // 50000
#define WS_CNT_Z   550002      // 50000
#define WS_CUR_X   600002      // 50000
#define WS_CUR_Z   650002      // 50000
#define WS_STAT    802402      // 132 u32: lookback status[2][64] + ticket[2]
#define WS_A1X     802816      // 6400000 ints = 25.6 MB bf16
#define WS_A1Z     7202816     // 6400000
#define SCAN_CHUNKS 49

// ---------------------------------------------------------------------------
__device__ __forceinline__ unsigned pack_bf16(float a, float b) {
    unsigned ua = __float_as_uint(a); ua += 0x7fff + ((ua >> 16) & 1);
    unsigned ub = __float_as_uint(b); ub += 0x7fff + ((ub >> 16) & 1);
    return (ua >> 16) | (ub & 0xffff0000u);
}

// MERGED hist + a1 (independent work, one launch; a1's FMA hides hist's
// atomic latency). blockIdx.y: 0 = hist (+ zero the scan lookback status),
// 1/2 = a1 channel 0/1.
// a1[ch][cn][b][32] = h_from[b,cn,:] @ W1[0:16,:] bf16 lane-interleaved:
// per-cn block of 64 uint4; lane b's p-th uint4 at block + p*16 + b.
// MASK FOLDED IN (validated R1-R8): syn==0 rows are bf16 -inf so the
// gather-side relu(a1+a2)==0 == mask*relu(...).
__global__ __launch_bounds__(256) void hist_a1_kernel(
    const int* __restrict__ ti_x, const int* __restrict__ ti_z,
    const float* __restrict__ h_from_x, const float* __restrict__ h_from_z,
    const int* __restrict__ syn_x, const int* __restrict__ syn_z,
    const float* __restrict__ Wx1, const float* __restrict__ Wz1,
    int* __restrict__ cnt_x, int* __restrict__ cnt_z,
    unsigned* __restrict__ stat,
    uint4* __restrict__ a1x, uint4* __restrict__ a1z)
{
    const int t = blockIdx.x * 256 + threadIdx.x;
    if (blockIdx.y == 0) {
        if (t < 132) stat[t] = 0;      // scan status+tickets, free zeroing
        if (t < NUM_E) {
            atomicAdd(&cnt_x[ti_x[t]], 1);
            atomicAdd(&cnt_z[ti_z[t]], 1);
        }
        return;
    }
    if (t >= NUM_CN * BATCH) return;
    const int ch = blockIdx.y - 1;
    const int b  = t & 15;
    const int cn = t >> 4;
    const float* hsrc = (ch ? h_from_z : h_from_x) + ((size_t)b * NUM_CN + cn) * D_EMBED;
    const float* W1   = ch ? Wz1 : Wx1;
    const bool on = ((ch ? syn_z : syn_x)[b * NUM_CN + cn] & 1) != 0;
    uint4* dst = (ch ? a1z : a1x) + (size_t)cn * 64;

    float hf[D_EMBED];
#pragma unroll
    for (int i = 0; i < 4; ++i) {
        float4 v = ((const float4*)hsrc)[i];
        hf[4 * i + 0] = v.x; hf[4 * i + 1] = v.y;
        hf[4 * i + 2] = v.z; hf[4 * i + 3] = v.w;
    }
    f32x2 a[16] = {};
#pragma unroll
    for (int i = 0; i < D_EMBED; ++i) {
        const float fi = hf[i];
        const f32x2* wv = (const f32x2*)(W1 + i * D_HIDDEN);
#pragma unroll
        for (int j = 0; j < 16; ++j)
            a[j] = fi * wv[j] + a[j];        // v_pk_fma_f32 via contract
    }
    unsigned u[16];
#pragma unroll
    for (int j = 0; j < 16; ++j)
        u[j] = on ? pack_bf16(a[j].x, a[j].y) : 0xFF80FF80u;
#pragma unroll
    for (int p = 0; p < 4; ++p) {
        uint4 q;
        q.x = u[4 * p + 0]; q.y = u[4 * p + 1];
        q.z = u[4 * p + 2]; q.w = u[4 * p + 3];
        dst[p * 16 + b] = q;
    }
}

// Single-pass decoupled-lookback scan: replaces scan1+scan3 (2 dispatches +
// incl round-trip -> 1 dispatch). Ticket-ordered virtual block ids guarantee
// every lookback predecessor has started (no dispatch-order assumption);
// publish/poll via device-scope atomics (G16: XCD L2s not coherent).
// status word: [31]=inclusive-ready, [30]=aggregate-ready, [29:0]=value.
__global__ __launch_bounds__(1024) void scan_kernel(
    const int* __restrict__ cnt_x, const int* __restrict__ cnt_z,
    unsigned* __restrict__ stat,
    int* __restrict__ off_x, int* __restrict__ off_z,
    int* __restrict__ cur_x, int* __restrict__ cur_z)
{
    const int ch = blockIdx.y;
    const int t  = threadIdx.x;
    __shared__ int s[1024];
    __shared__ int vb_sh, base_sh;
    unsigned* st = stat + ch * 64;
    if (t == 0) vb_sh = (int)atomicAdd(&stat[128 + ch], 1u);
    __syncthreads();
    const int vb  = vb_sh;
    const int gid = vb * 1024 + t;
    const int* cnt = ch ? cnt_z : cnt_x;
    int* off = ch ? off_z : off_x;
    int* cur = ch ? cur_z : cur_x;
    const int c = (gid < NUM_VN) ? cnt[gid] : 0;
    s[t] = c;
    __syncthreads();
#pragma unroll
    for (int d = 1; d < 1024; d <<= 1) {
        int x = 0;
        if (t >= d) x = s[t - d];
        __syncthreads();
        if (t >= d) s[t] += x;
        __syncthreads();
    }
    if (t == 1023) atomicExch(&st[vb], (1u << 30) | (unsigned)s[1023]);
    if (t == 0) {
        int base = 0;
        for (int j = vb - 1; j >= 0; ) {
            unsigned v = atomicOr(&st[j], 0u);
            if (v == 0u) continue;           // not published yet: spin
            base += (int)(v & 0x3fffffffu);
            if (v & 0x80000000u) break;      // inclusive: done
            --j;                             // aggregate: keep walking back
        }
        base_sh = base;
    }
    __syncthreads();
    const int base = base_sh;
    if (t == 1023)
        atomicExch(&st[vb], 0x80000000u | (unsigned)(base + s[1023]));
    if (gid < NUM_VN) {
        int iv = base + s[t];
        off[gid + 1] = iv;
        cur[gid]     = iv - c;
    }
    if (vb == 0 && t == 0) off[0] = 0;
}

// fill: CSR slot stores the FROM node id directly.
__global__ __launch_bounds__(256) void fill_kernel(
    const int* __restrict__ ti_x, const int* __restrict__ ti_z,
    const int* __restrict__ fi_x, const int* __restrict__ fi_z,
    int* __restrict__ cur_x, int* __restrict__ cur_z,
    int* __restrict__ ids_x, int* __restrict__ ids_z)
{
    int e = blockIdx.x * 256 + threadIdx.x;
    if (e >= NUM_E) return;
    int px = atomicAdd(&cur_x[ti_x[e]], 1);
    ids_x[px] = fi_x[e];
    int pz = atomicAdd(&cur_z[ti_z[e]], 1);
    ids_z[pz] = fi_z[e];
}

// ---------------------------------------------------------------------------
// Gather: 110.5us PROVEN (R9 counters: VGPR 64 = top wave tier, occ 35%,
// VALU 48%). UNTOUCHED this round — it is the control. Structure log:
// packed-fp32 (R7, -16us), per-channel immediate store (R8, -27us via
// 64-VGPR tier). Session rules: no min-wave pins (3x catastrophic spills),
// single-edge loop (R4), no fusion (R1), no split (R3/R5).
__device__ __forceinline__ void acc4(
    unsigned w0, unsigned w1, unsigned w2, unsigned w3,
    const f32x2* __restrict__ a2, f32x2* __restrict__ hacc)
{
    const f32x2 z2 = {0.0f, 0.0f};
    unsigned ww[4] = {w0, w1, w2, w3};
#pragma unroll
    for (int j = 0; j < 4; ++j) {
        f32x2 v;
        v.x = __uint_as_float(ww[j] << 16);
        v.y = __uint_as_float(ww[j] & 0xffff0000u);
        f32x2 s = a2[j] + v;                  // pk_add
        s = __builtin_elementwise_max(s, z2); // pk_max
        hacc[j] += s;                         // pk_add
    }
}

__device__ __forceinline__ void channel_accum_store(
    const float* __restrict__ h_to_slot, int n, int b,
    const int* __restrict__ off, const int* __restrict__ ids,
    const uint4* __restrict__ a1,
    const float* __restrict__ W1, const float* __restrict__ W2,
    uint4* __restrict__ dst2)   // writes dst2[0], dst2[1]
{
    // reload ht per channel: 4 cache-hit loads < 16 live registers
    float ht[D_EMBED];
#pragma unroll
    for (int i = 0; i < 4; ++i) {
        float4 v = ((const float4*)h_to_slot)[i];
        ht[4 * i + 0] = v.x; ht[4 * i + 1] = v.y;
        ht[4 * i + 2] = v.z; ht[4 * i + 3] = v.w;
    }
    f32x2 a2[16] = {};
#pragma unroll
    for (int i = 0; i < D_EMBED; ++i) {
        const float hi = ht[i];
        const f32x2* wv = (const f32x2*)(W1 + (D_EMBED + i) * D_HIDDEN);
#pragma unroll
        for (int p = 0; p < 16; ++p)
            a2[p] = hi * wv[p] + a2[p];          // pk_fma
    }

    f32x2 hacc[16] = {};

    const int ks = off[n], ke = off[n + 1];
    for (int k = ks; k < ke; ++k) {
        const uint4* pa = a1 + (size_t)ids[k] * 64 + b;
        uint4 q0 = pa[0], q1 = pa[16], q2 = pa[32], q3 = pa[48];
        acc4(q0.x, q0.y, q0.z, q0.w, a2 + 0,  hacc + 0);
        acc4(q1.x, q1.y, q1.z, q1.w, a2 + 4,  hacc + 4);
        acc4(q2.x, q2.y, q2.z, q2.w, a2 + 8,  hacc + 8);
        acc4(q3.x, q3.y, q3.z, q3.w, a2 + 12, hacc + 12);
    }

    f32x2 m2[8] = {};
#pragma unroll
    for (int p = 0; p < 16; ++p) {
        const float h0 = hacc[p].x, h1 = hacc[p].y;
        const f32x2* w0 = (const f32x2*)(W2 + (2 * p) * D_MSG);
        const f32x2* w1 = (const f32x2*)(W2 + (2 * p + 1) * D_MSG);
#pragma unroll
        for (int j = 0; j < 8; ++j)
            m2[j] = h0 * w0[j] + (h1 * w1[j] + m2[j]);   // 2x pk_fma
    }
    uint4 q;
    q.x = pack_bf16(m2[0].x, m2[0].y); q.y = pack_bf16(m2[1].x, m2[1].y);
    q.z = pack_bf16(m2[2].x, m2[2].y); q.w = pack_bf16(m2[3].x, m2[3].y);
    dst2[0] = q;
    q.x = pack_bf16(m2[4].x, m2[4].y); q.y = pack_bf16(m2[5].x, m2[5].y);
    q.z = pack_bf16(m2[6].x, m2[6].y); q.w = pack_bf16(m2[7].x, m2[7].y);
    dst2[1] = q;
}

// gather: thread=(n,b); writes packed bf16 {mx|mz} (64 B) into the thread's
// OWN final-output slot in d_out (node kernel reads then overwrites it).
__global__ __launch_bounds__(256) void gather_kernel(
    const float* __restrict__ h_to,
    const int* __restrict__ off_x, const int* __restrict__ ids_x,
    const int* __restrict__ off_z, const int* __restrict__ ids_z,
    const uint4* __restrict__ a1x, const uint4* __restrict__ a1z,
    const float* __restrict__ Wx1, const float* __restrict__ Wx2,
    const float* __restrict__ Wz1, const float* __restrict__ Wz2,
    uint4* __restrict__ out_m)
{
    const int t = blockIdx.x * 256 + threadIdx.x;
    if (t >= NUM_VN * BATCH) return;
    const int b = t & (BATCH - 1);
    const int n = t >> 4;
    const size_t slot = (size_t)b * NUM_VN + n;
    const float* ht_slot = h_to + slot * D_EMBED;
    uint4* dst = out_m + slot * 4;

    channel_accum_store(ht_slot, n, b, off_x, ids_x, a1x, Wx1, Wx2, dst);
    channel_accum_store(ht_slot, n, b, off_z, ids_z, a1z, Wz1, Wz2, dst + 2);
}

// node MLP: reads its own slot {mx|mz} + h_to, computes 48->32(relu)->16,
// overwrites the slot with the final fp32 output. Packed-fp32 variant.
__global__ __launch_bounds__(256) void node_kernel(
    const float* __restrict__ h_to,
    const float* __restrict__ We1, const float* __restrict__ We2,
    float* out)
{
    const f32x2 z2 = {0.0f, 0.0f};
    const int t = blockIdx.x * 256 + threadIdx.x;
    if (t >= NUM_VN * BATCH) return;
    const int b = t & (BATCH - 1);
    const int n = t >> 4;
    const size_t slot = (size_t)b * NUM_VN + n;

    const uint4* pm = (const uint4*)out + slot * 4;
    uint4 q0 = pm[0], q1 = pm[1], q2 = pm[2], q3 = pm[3];
    unsigned uu[16] = {q0.x, q0.y, q0.z, q0.w,
                       q1.x, q1.y, q1.z, q1.w,
                       q2.x, q2.y, q2.z, q2.w,
                       q3.x, q3.y, q3.z, q3.w};
    float f[48];
#pragma unroll
    for (int p = 0; p < 16; ++p) {
        f[2 * p]     = __uint_as_float(uu[p] << 16);
        f[2 * p + 1] = __uint_as_float(uu[p] & 0xffff0000u);
    }
#pragma unroll
    for (int i = 0; i < 4; ++i) {
        float4 v = ((const float4*)(h_to + slot * D_EMBED))[i];
        f[32 + 4 * i + 0] = v.x; f[32 + 4 * i + 1] = v.y;
        f[32 + 4 * i + 2] = v.z; f[32 + 4 * i + 3] = v.w;
    }

    f32x2 hid[16] = {};
#pragma unroll
    for (int i = 0; i < 48; ++i) {
        const float fi = f[i];
        const f32x2* wv = (const f32x2*)(We1 + i * D_HIDDEN);
#pragma unroll
        for (int p = 0; p < 16; ++p)
            hid[p] = fi * wv[p] + hid[p];
    }
#pragma unroll
    for (int p = 0; p < 16; ++p)
        hid[p] = __builtin_elementwise_max(hid[p], z2);

    f32x2 o2[8] = {};
#pragma unroll
    for (int p = 0; p < 16; ++p) {
        const float h0 = hid[p].x, h1 = hid[p].y;
        const f32x2* w0 = (const f32x2*)(We2 + (2 * p) * D_EMBED);
        const f32x2* w1 = (const f32x2*)(We2 + (2 * p + 1) * D_EMBED);
#pragma unroll
        for (int j = 0; j < 8; ++j)
            o2[j] = h0 * w0[j] + (h1 * w1[j] + o2[j]);
    }

#pragma unroll
    for (int i = 0; i < 4; ++i) {
        float4 v;
        v.x = o2[2 * i].x;     v.y = o2[2 * i].y;
        v.z = o2[2 * i + 1].x; v.w = o2[2 * i + 1].y;
        ((float4*)(out + slot * D_EMBED))[i] = v;
    }
}

// ---------------------------------------------------------------------------
extern "C" void kernel_launch(void* const* d_in, const int* in_sizes, int n_in,
                              void* d_out, int out_size, void* d_ws, size_t ws_size,
                              hipStream_t stream) {
    const float* h_from_x = (const float*)d_in[0];
    const float* h_from_z = (const float*)d_in[1];
    const float* h_to     = (const float*)d_in[2];
    const int*   syn_x    = (const int*)d_in[3];
    const int*   syn_z    = (const int*)d_in[4];
    const int*   fi_x     = (const int*)d_in[5];
    const int*   ti_x     = (const int*)d_in[6];
    const int*   fi_z     = (const int*)d_in[7];
    const int*   ti_z     = (const int*)d_in[8];
    const float* Wx1      = (const float*)d_in[9];
    const float* Wx2      = (const float*)d_in[10];
    const float* Wz1      = (const float*)d_in[11];
    const float* Wz2      = (const float*)d_in[12];
    const float* We1      = (const float*)d_in[13];
    const float* We2      = (const float*)d_in[14];

    int* ws = (int*)d_ws;
    int* ids_x  = ws + WS_IDS_X;
    int* ids_z  = ws + WS_IDS_Z;
    int* off_x  = ws + WS_OFF_X;
    int* off_z  = ws + WS_OFF_Z;
    int* cnt_x  = ws + WS_CNT_X;
    int* cnt_z  = ws + WS_CNT_Z;
    int* cur_x  = ws + WS_CUR_X;
    int* cur_z  = ws + WS_CUR_Z;
    unsigned* stat = (unsigned*)(ws + WS_STAT);
    uint4* a1x  = (uint4*)(ws + WS_A1X);
    uint4* a1z  = (uint4*)(ws + WS_A1Z);

    hipMemsetAsync(cnt_x, 0, 2 * NUM_VN * sizeof(int), stream);

    // hist + a1 in one launch (independent; y=0 hist+stat-zero, y=1/2 a1)
    hist_a1_kernel<<<dim3((NUM_CN * BATCH + 255) / 256, 3), dim3(256), 0, stream>>>(
        ti_x, ti_z, h_from_x, h_from_z, syn_x, syn_z, Wx1, Wz1,
        cnt_x, cnt_z, stat, a1x, a1z);
    scan_kernel<<<dim3(SCAN_CHUNKS, 2), dim3(1024), 0, stream>>>(
        cnt_x, cnt_z, stat, off_x, off_z, cur_x, cur_z);
    fill_kernel<<<dim3((NUM_E + 255) / 256), dim3(256), 0, stream>>>(
        ti_x, ti_z, fi_x, fi_z, cur_x, cur_z, ids_x, ids_z);

    gather_kernel<<<dim3((NUM_VN * BATCH) / 256), dim3(256), 0, stream>>>(
        h_to, off_x, ids_x, off_z, ids_z, a1x, a1z,
        Wx1, Wx2, Wz1, Wz2, (uint4*)d_out);

    node_kernel<<<dim3((NUM_VN * BATCH) / 256), dim3(256), 0, stream>>>(
        h_to, We1, We2, (float*)d_out);
}

// Round 11
// 355.776 us; speedup vs baseline: 1.0181x; 1.0181x over previous
//
#include <hip/hip_runtime.h>

#define NUM_CN   25000
#define NUM_VN   50000
#define NUM_E    200000
#define D_EMBED  16
#define D_HIDDEN 32
#define D_MSG    16
#define BATCH    16

typedef float f32x2 __attribute__((ext_vector_type(2)));

// ---------------------------------------------------------------------------
// Workspace layout (int units) — 54.41 MB total (proven available):
#define WS_IDS_X   0           // 200000  (stores FROM node ids, CSR order)
#define WS_IDS_Z   200000      // 200000
#define WS_OFF_X   400000      // 50001
#define WS_OFF_Z   450001      // 50001
#define WS_CNT_X   500002      // 50000
#define WS_CNT_Z   550002      // 50000
#define WS_CUR_X   600002      // 50000
#define WS_CUR_Z   650002      // 50000
#define WS_STAT    802402      // 132 u32: lookback status[2][64] + ticket[2]
#define WS_A1X     802816      // 6400000 ints = 25.6 MB bf16
#define WS_A1Z     7202816     // 6400000
#define SCAN_CHUNKS 49

// ---------------------------------------------------------------------------
__device__ __forceinline__ unsigned pack_bf16(float a, float b) {
    unsigned ua = __float_as_uint(a); ua += 0x7fff + ((ua >> 16) & 1);
    unsigned ub = __float_as_uint(b); ub += 0x7fff + ((ub >> 16) & 1);
    return (ua >> 16) | (ub & 0xffff0000u);
}

// MERGED hist + a1 (independent work, one launch; a1's FMA hides hist's
// atomic latency). blockIdx.y: 0 = hist (+ zero the scan lookback status),
// 1/2 = a1 channel 0/1.
// a1[ch][cn][b][32] = h_from[b,cn,:] @ W1[0:16,:] bf16 lane-interleaved:
// per-cn block of 64 uint4; lane b's p-th uint4 at block + p*16 + b.
// MASK FOLDED IN (validated R1-R9): syn==0 rows are bf16 -inf so the
// gather-side relu(a1+a2)==0 == mask*relu(...).
__global__ __launch_bounds__(256) void hist_a1_kernel(
    const int* __restrict__ ti_x, const int* __restrict__ ti_z,
    const float* __restrict__ h_from_x, const float* __restrict__ h_from_z,
    const int* __restrict__ syn_x, const int* __restrict__ syn_z,
    const float* __restrict__ Wx1, const float* __restrict__ Wz1,
    int* __restrict__ cnt_x, int* __restrict__ cnt_z,
    unsigned* __restrict__ stat,
    uint4* __restrict__ a1x, uint4* __restrict__ a1z)
{
    const int t = blockIdx.x * 256 + threadIdx.x;
    if (blockIdx.y == 0) {
        if (t < 132) stat[t] = 0;      // scan status+tickets, free zeroing
        if (t < NUM_E) {
            atomicAdd(&cnt_x[ti_x[t]], 1);
            atomicAdd(&cnt_z[ti_z[t]], 1);
        }
        return;
    }
    if (t >= NUM_CN * BATCH) return;
    const int ch = blockIdx.y - 1;
    const int b  = t & 15;
    const int cn = t >> 4;
    const float* hsrc = (ch ? h_from_z : h_from_x) + ((size_t)b * NUM_CN + cn) * D_EMBED;
    const float* W1   = ch ? Wz1 : Wx1;
    const bool on = ((ch ? syn_z : syn_x)[b * NUM_CN + cn] & 1) != 0;
    uint4* dst = (ch ? a1z : a1x) + (size_t)cn * 64;

    float hf[D_EMBED];
#pragma unroll
    for (int i = 0; i < 4; ++i) {
        float4 v = ((const float4*)hsrc)[i];
        hf[4 * i + 0] = v.x; hf[4 * i + 1] = v.y;
        hf[4 * i + 2] = v.z; hf[4 * i + 3] = v.w;
    }
    f32x2 a[16] = {};
#pragma unroll
    for (int i = 0; i < D_EMBED; ++i) {
        const float fi = hf[i];
        const f32x2* wv = (const f32x2*)(W1 + i * D_HIDDEN);
#pragma unroll
        for (int j = 0; j < 16; ++j)
            a[j] = fi * wv[j] + a[j];        // v_pk_fma_f32 via contract
    }
    unsigned u[16];
#pragma unroll
    for (int j = 0; j < 16; ++j)
        u[j] = on ? pack_bf16(a[j].x, a[j].y) : 0xFF80FF80u;
#pragma unroll
    for (int p = 0; p < 4; ++p) {
        uint4 q;
        q.x = u[4 * p + 0]; q.y = u[4 * p + 1];
        q.z = u[4 * p + 2]; q.w = u[4 * p + 3];
        dst[p * 16 + b] = q;
    }
}

// Single-pass decoupled-lookback scan (R9: neutral vs 2-kernel scan, kept
// for the smaller dispatch count). Ticket-ordered virtual block ids; device
// atomics for publish/poll (G16). status: [31]=incl, [30]=agg, [29:0]=val.
__global__ __launch_bounds__(1024) void scan_kernel(
    const int* __restrict__ cnt_x, const int* __restrict__ cnt_z,
    unsigned* __restrict__ stat,
    int* __restrict__ off_x, int* __restrict__ off_z,
    int* __restrict__ cur_x, int* __restrict__ cur_z)
{
    const int ch = blockIdx.y;
    const int t  = threadIdx.x;
    __shared__ int s[1024];
    __shared__ int vb_sh, base_sh;
    unsigned* st = stat + ch * 64;
    if (t == 0) vb_sh = (int)atomicAdd(&stat[128 + ch], 1u);
    __syncthreads();
    const int vb  = vb_sh;
    const int gid = vb * 1024 + t;
    const int* cnt = ch ? cnt_z : cnt_x;
    int* off = ch ? off_z : off_x;
    int* cur = ch ? cur_z : cur_x;
    const int c = (gid < NUM_VN) ? cnt[gid] : 0;
    s[t] = c;
    __syncthreads();
#pragma unroll
    for (int d = 1; d < 1024; d <<= 1) {
        int x = 0;
        if (t >= d) x = s[t - d];
        __syncthreads();
        if (t >= d) s[t] += x;
        __syncthreads();
    }
    if (t == 1023) atomicExch(&st[vb], (1u << 30) | (unsigned)s[1023]);
    if (t == 0) {
        int base = 0;
        for (int j = vb - 1; j >= 0; ) {
            unsigned v = atomicOr(&st[j], 0u);
            if (v == 0u) continue;           // not published yet: spin
            base += (int)(v & 0x3fffffffu);
            if (v & 0x80000000u) break;      // inclusive: done
            --j;                             // aggregate: keep walking back
        }
        base_sh = base;
    }
    __syncthreads();
    const int base = base_sh;
    if (t == 1023)
        atomicExch(&st[vb], 0x80000000u | (unsigned)(base + s[1023]));
    if (gid < NUM_VN) {
        int iv = base + s[t];
        off[gid + 1] = iv;
        cur[gid]     = iv - c;
    }
    if (vb == 0 && t == 0) off[0] = 0;
}

// fill: CSR slot stores the FROM node id directly.
__global__ __launch_bounds__(256) void fill_kernel(
    const int* __restrict__ ti_x, const int* __restrict__ ti_z,
    const int* __restrict__ fi_x, const int* __restrict__ fi_z,
    int* __restrict__ cur_x, int* __restrict__ cur_z,
    int* __restrict__ ids_x, int* __restrict__ ids_z)
{
    int e = blockIdx.x * 256 + threadIdx.x;
    if (e >= NUM_E) return;
    int px = atomicAdd(&cur_x[ti_x[e]], 1);
    ids_x[px] = fi_x[e];
    int pz = atomicAdd(&cur_z[ti_z[e]], 1);
    ids_z[pz] = fi_z[e];
}

// ---------------------------------------------------------------------------
// Gather: 110.5us PROVEN (VGPR 64 = top wave tier, occ 35%, VALU 48%).
// UNTOUCHED this round — control. Structure log: packed-fp32 (R7, -16us),
// per-channel immediate store (R8, -27us via 64-VGPR tier). Session rules:
// no min-wave pins (3x spills), single-edge loop (R4), no fusion (R1),
// no split (R3/R5).
__device__ __forceinline__ void acc4(
    unsigned w0, unsigned w1, unsigned w2, unsigned w3,
    const f32x2* __restrict__ a2, f32x2* __restrict__ hacc)
{
    const f32x2 z2 = {0.0f, 0.0f};
    unsigned ww[4] = {w0, w1, w2, w3};
#pragma unroll
    for (int j = 0; j < 4; ++j) {
        f32x2 v;
        v.x = __uint_as_float(ww[j] << 16);
        v.y = __uint_as_float(ww[j] & 0xffff0000u);
        f32x2 s = a2[j] + v;                  // pk_add
        s = __builtin_elementwise_max(s, z2); // pk_max
        hacc[j] += s;                         // pk_add
    }
}

__device__ __forceinline__ void channel_accum_store(
    const float* __restrict__ h_to_slot, int n, int b,
    const int* __restrict__ off, const int* __restrict__ ids,
    const uint4* __restrict__ a1,
    const float* __restrict__ W1, const float* __restrict__ W2,
    uint4* __restrict__ dst2)   // writes dst2[0], dst2[1]
{
    // reload ht per channel: 4 cache-hit loads < 16 live registers
    float ht[D_EMBED];
#pragma unroll
    for (int i = 0; i < 4; ++i) {
        float4 v = ((const float4*)h_to_slot)[i];
        ht[4 * i + 0] = v.x; ht[4 * i + 1] = v.y;
        ht[4 * i + 2] = v.z; ht[4 * i + 3] = v.w;
    }
    f32x2 a2[16] = {};
#pragma unroll
    for (int i = 0; i < D_EMBED; ++i) {
        const float hi = ht[i];
        const f32x2* wv = (const f32x2*)(W1 + (D_EMBED + i) * D_HIDDEN);
#pragma unroll
        for (int p = 0; p < 16; ++p)
            a2[p] = hi * wv[p] + a2[p];          // pk_fma
    }

    f32x2 hacc[16] = {};

    const int ks = off[n], ke = off[n + 1];
    for (int k = ks; k < ke; ++k) {
        const uint4* pa = a1 + (size_t)ids[k] * 64 + b;
        uint4 q0 = pa[0], q1 = pa[16], q2 = pa[32], q3 = pa[48];
        acc4(q0.x, q0.y, q0.z, q0.w, a2 + 0,  hacc + 0);
        acc4(q1.x, q1.y, q1.z, q1.w, a2 + 4,  hacc + 4);
        acc4(q2.x, q2.y, q2.z, q2.w, a2 + 8,  hacc + 8);
        acc4(q3.x, q3.y, q3.z, q3.w, a2 + 12, hacc + 12);
    }

    f32x2 m2[8] = {};
#pragma unroll
    for (int p = 0; p < 16; ++p) {
        const float h0 = hacc[p].x, h1 = hacc[p].y;
        const f32x2* w0 = (const f32x2*)(W2 + (2 * p) * D_MSG);
        const f32x2* w1 = (const f32x2*)(W2 + (2 * p + 1) * D_MSG);
#pragma unroll
        for (int j = 0; j < 8; ++j)
            m2[j] = h0 * w0[j] + (h1 * w1[j] + m2[j]);   // 2x pk_fma
    }
    uint4 q;
    q.x = pack_bf16(m2[0].x, m2[0].y); q.y = pack_bf16(m2[1].x, m2[1].y);
    q.z = pack_bf16(m2[2].x, m2[2].y); q.w = pack_bf16(m2[3].x, m2[3].y);
    dst2[0] = q;
    q.x = pack_bf16(m2[4].x, m2[4].y); q.y = pack_bf16(m2[5].x, m2[5].y);
    q.z = pack_bf16(m2[6].x, m2[6].y); q.w = pack_bf16(m2[7].x, m2[7].y);
    dst2[1] = q;
}

// gather: thread=(n,b); writes packed bf16 {mx|mz} (64 B) into the thread's
// OWN final-output slot in d_out (node kernel reads then overwrites it).
__global__ __launch_bounds__(256) void gather_kernel(
    const float* __restrict__ h_to,
    const int* __restrict__ off_x, const int* __restrict__ ids_x,
    const int* __restrict__ off_z, const int* __restrict__ ids_z,
    const uint4* __restrict__ a1x, const uint4* __restrict__ a1z,
    const float* __restrict__ Wx1, const float* __restrict__ Wx2,
    const float* __restrict__ Wz1, const float* __restrict__ Wz2,
    uint4* __restrict__ out_m)
{
    const int t = blockIdx.x * 256 + threadIdx.x;
    if (t >= NUM_VN * BATCH) return;
    const int b = t & (BATCH - 1);
    const int n = t >> 4;
    const size_t slot = (size_t)b * NUM_VN + n;
    const float* ht_slot = h_to + slot * D_EMBED;
    uint4* dst = out_m + slot * 4;

    channel_accum_store(ht_slot, n, b, off_x, ids_x, a1x, Wx1, Wx2, dst);
    channel_accum_store(ht_slot, n, b, off_z, ids_z, a1z, Wz1, Wz2, dst + 2);
}

// ---------------------------------------------------------------------------
// node MLP, THIS ROUND'S change: liveness-first restructure. Old version
// staged f[48] + uu[16] as live arrays (est ~100 VGPR -> 5-wave tier). Now
// each packed message word / ht float4 is consumed into hid IMMEDIATELY
// (2 resp. 4 feats x 16 pk-fma), never materializing the feature vector.
// ht is loaded AFTER the message words are consumed so the q-registers are
// dead first. Peak live ~= hid(32) + one uint4 + addr -> target <=64 VGPR
// = 8-wave tier (the R8 gather lever). Same FLOPs, same order -> bitwise
// identical output. No pin (session rule).
__device__ __forceinline__ void nfeat2(
    unsigned w, const float* __restrict__ wrow, f32x2* __restrict__ hid)
{
    const float flo = __uint_as_float(w << 16);
    const float fhi = __uint_as_float(w & 0xffff0000u);
    const f32x2* w0 = (const f32x2*)wrow;
    const f32x2* w1 = (const f32x2*)(wrow + D_HIDDEN);
#pragma unroll
    for (int p = 0; p < 16; ++p)
        hid[p] = flo * w0[p] + (fhi * w1[p] + hid[p]);
}

__device__ __forceinline__ void nfeat4(
    float4 v, const float* __restrict__ wrow, f32x2* __restrict__ hid)
{
    const float ff[4] = {v.x, v.y, v.z, v.w};
#pragma unroll
    for (int j = 0; j < 4; ++j) {
        const float fj = ff[j];
        const f32x2* wv = (const f32x2*)(wrow + j * D_HIDDEN);
#pragma unroll
        for (int p = 0; p < 16; ++p)
            hid[p] = fj * wv[p] + hid[p];
    }
}

__global__ __launch_bounds__(256) void node_kernel(
    const float* __restrict__ h_to,
    const float* __restrict__ We1, const float* __restrict__ We2,
    float* out)
{
    const f32x2 z2 = {0.0f, 0.0f};
    const int t = blockIdx.x * 256 + threadIdx.x;
    if (t >= NUM_VN * BATCH) return;
    const int b = t & (BATCH - 1);
    const int n = t >> 4;
    const size_t slot = (size_t)b * NUM_VN + n;

    const uint4* pm = (const uint4*)out + slot * 4;
    uint4 q0 = pm[0], q1 = pm[1], q2 = pm[2], q3 = pm[3];

    f32x2 hid[16] = {};
    nfeat2(q0.x, We1 +  0 * D_HIDDEN, hid);
    nfeat2(q0.y, We1 +  2 * D_HIDDEN, hid);
    nfeat2(q0.z, We1 +  4 * D_HIDDEN, hid);
    nfeat2(q0.w, We1 +  6 * D_HIDDEN, hid);
    nfeat2(q1.x, We1 +  8 * D_HIDDEN, hid);
    nfeat2(q1.y, We1 + 10 * D_HIDDEN, hid);
    nfeat2(q1.z, We1 + 12 * D_HIDDEN, hid);
    nfeat2(q1.w, We1 + 14 * D_HIDDEN, hid);
    nfeat2(q2.x, We1 + 16 * D_HIDDEN, hid);
    nfeat2(q2.y, We1 + 18 * D_HIDDEN, hid);
    nfeat2(q2.z, We1 + 20 * D_HIDDEN, hid);
    nfeat2(q2.w, We1 + 22 * D_HIDDEN, hid);
    nfeat2(q3.x, We1 + 24 * D_HIDDEN, hid);
    nfeat2(q3.y, We1 + 26 * D_HIDDEN, hid);
    nfeat2(q3.z, We1 + 28 * D_HIDDEN, hid);
    nfeat2(q3.w, We1 + 30 * D_HIDDEN, hid);

    // ht feats 32..47, loaded after message words are dead
    const float4* ht4 = (const float4*)(h_to + slot * D_EMBED);
    float4 v0 = ht4[0], v1 = ht4[1], v2 = ht4[2], v3 = ht4[3];
    nfeat4(v0, We1 + 32 * D_HIDDEN, hid);
    nfeat4(v1, We1 + 36 * D_HIDDEN, hid);
    nfeat4(v2, We1 + 40 * D_HIDDEN, hid);
    nfeat4(v3, We1 + 44 * D_HIDDEN, hid);

#pragma unroll
    for (int p = 0; p < 16; ++p)
        hid[p] = __builtin_elementwise_max(hid[p], z2);

    f32x2 o2[8] = {};
#pragma unroll
    for (int p = 0; p < 16; ++p) {
        const float h0 = hid[p].x, h1 = hid[p].y;
        const f32x2* w0 = (const f32x2*)(We2 + (2 * p) * D_EMBED);
        const f32x2* w1 = (const f32x2*)(We2 + (2 * p + 1) * D_EMBED);
#pragma unroll
        for (int j = 0; j < 8; ++j)
            o2[j] = h0 * w0[j] + (h1 * w1[j] + o2[j]);
    }

#pragma unroll
    for (int i = 0; i < 4; ++i) {
        float4 v;
        v.x = o2[2 * i].x;     v.y = o2[2 * i].y;
        v.z = o2[2 * i + 1].x; v.w = o2[2 * i + 1].y;
        ((float4*)(out + slot * D_EMBED))[i] = v;
    }
}

// ---------------------------------------------------------------------------
extern "C" void kernel_launch(void* const* d_in, const int* in_sizes, int n_in,
                              void* d_out, int out_size, void* d_ws, size_t ws_size,
                              hipStream_t stream) {
    const float* h_from_x = (const float*)d_in[0];
    const float* h_from_z = (const float*)d_in[1];
    const float* h_to     = (const float*)d_in[2];
    const int*   syn_x    = (const int*)d_in[3];
    const int*   syn_z    = (const int*)d_in[4];
    const int*   fi_x     = (const int*)d_in[5];
    const int*   ti_x     = (const int*)d_in[6];
    const int*   fi_z     = (const int*)d_in[7];
    const int*   ti_z     = (const int*)d_in[8];
    const float* Wx1      = (const float*)d_in[9];
    const float* Wx2      = (const float*)d_in[10];
    const float* Wz1      = (const float*)d_in[11];
    const float* Wz2      = (const float*)d_in[12];
    const float* We1      = (const float*)d_in[13];
    const float* We2      = (const float*)d_in[14];

    int* ws = (int*)d_ws;
    int* ids_x  = ws + WS_IDS_X;
    int* ids_z  = ws + WS_IDS_Z;
    int* off_x  = ws + WS_OFF_X;
    int* off_z  = ws + WS_OFF_Z;
    int* cnt_x  = ws + WS_CNT_X;
    int* cnt_z  = ws + WS_CNT_Z;
    int* cur_x  = ws + WS_CUR_X;
    int* cur_z  = ws + WS_CUR_Z;
    unsigned* stat = (unsigned*)(ws + WS_STAT);
    uint4* a1x  = (uint4*)(ws + WS_A1X);
    uint4* a1z  = (uint4*)(ws + WS_A1Z);

    hipMemsetAsync(cnt_x, 0, 2 * NUM_VN * sizeof(int), stream);

    // hist + a1 in one launch (independent; y=0 hist+stat-zero, y=1/2 a1)
    hist_a1_kernel<<<dim3((NUM_CN * BATCH + 255) / 256, 3), dim3(256), 0, stream>>>(
        ti_x, ti_z, h_from_x, h_from_z, syn_x, syn_z, Wx1, Wz1,
        cnt_x, cnt_z, stat, a1x, a1z);
    scan_kernel<<<dim3(SCAN_CHUNKS, 2), dim3(1024), 0, stream>>>(
        cnt_x, cnt_z, stat, off_x, off_z, cur_x, cur_z);
    fill_kernel<<<dim3((NUM_E + 255) / 256), dim3(256), 0, stream>>>(
        ti_x, ti_z, fi_x, fi_z, cur_x, cur_z, ids_x, ids_z);

    gather_kernel<<<dim3((NUM_VN * BATCH) / 256), dim3(256), 0, stream>>>(
        h_to, off_x, ids_x, off_z, ids_z, a1x, a1z,
        Wx1, Wx2, Wz1, Wz2, (uint4*)d_out);

    node_kernel<<<dim3((NUM_VN * BATCH) / 256), dim3(256), 0, stream>>>(
        h_to, We1, We2, (float*)d_out);
}